// Round 4
// baseline (30546.042 us; speedup 1.0000x reference)
//
#include <hip/hip_runtime.h>

#define VOCAB 32000
#define EMB   1024
#define HID   1024
#define SEQ   128
#define BATCH 32
#define ROWS  (SEQ * BATCH)   // 4096
#define G4    (4 * HID)       // 4096

// ---------------- int64-vs-int32 input_seq detection ----------------
__global__ void detect_i64(const unsigned int* __restrict__ w, int* __restrict__ flag) {
  __shared__ unsigned int s[256];
  unsigned int v = 0;
  for (int i = threadIdx.x; i < 2048; i += 256) v |= w[2 * i + 1];
  s[threadIdx.x] = v;
  __syncthreads();
  if (threadIdx.x == 0) {
    unsigned int o = 0;
    for (int i = 0; i < 256; ++i) o |= s[i];
    *flag = (o == 0u) ? 1 : 0;
  }
}

// ---------------- layer-0 z: x gathered from embedding, all f32 ----------------
// grid dim3(16, 32): bx -> n-slice of 256, by -> batch b. One launch per t.
__global__ __launch_bounds__(256) void z0_kernel(
    const int* ids, const int* flag, const float* emb, const float* h,
    const float* W, const float* bvec, float* z, int t) {
  int n = blockIdx.x * 256 + threadIdx.x;   // [0, 4096)
  int b = blockIdx.y;                       // [0, 32)
  int r = t * BATCH + b;
  int tok = (*flag) ? ids[2 * r] : ids[r];
  const float* x  = emb + (size_t)tok * EMB;
  const float* hb = h + b * HID;
  float acc = bvec[n];
  for (int k = 0; k < EMB; ++k) acc += x[k]  * W[(size_t)k * G4 + n];
  for (int k = 0; k < HID; ++k) acc += hb[k] * W[(size_t)(EMB + k) * G4 + n];
  z[b * G4 + n] = acc;
}

// ---------------- layer-1 z: x = h1 (f32) ----------------
__global__ __launch_bounds__(256) void z1_kernel(
    const float* x, const float* h, const float* W, const float* bvec, float* z) {
  int n = blockIdx.x * 256 + threadIdx.x;
  int b = blockIdx.y;
  const float* xb = x + b * HID;
  const float* hb = h + b * HID;
  float acc = bvec[n];
  for (int k = 0; k < HID; ++k) acc += xb[k] * W[(size_t)k * G4 + n];
  for (int k = 0; k < HID; ++k) acc += hb[k] * W[(size_t)(HID + k) * G4 + n];
  z[b * G4 + n] = acc;
}

// ---------------- gates: z -> (c, h), optionally record h sequence ----------------
__global__ __launch_bounds__(256) void gates_kernel(
    const float* z, float* c, float* h, float* hseq, int t) {
  int gid = blockIdx.x * 256 + threadIdx.x;  // 32768 = 32*1024
  int b = gid >> 10, u = gid & 1023;
  float iv = z[b * G4 + u];
  float jv = z[b * G4 + 1024 + u];
  float fv = z[b * G4 + 2048 + u];
  float ov = z[b * G4 + 3072 + u];
  float si = 1.f / (1.f + expf(-iv));
  float sf = 1.f / (1.f + expf(-(fv + 1.f)));   // FORGET_BIAS = 1.0
  float so = 1.f / (1.f + expf(-ov));
  float tj = tanhf(jv);
  float c2 = c[gid] * sf + si * tj;
  c[gid] = c2;
  float hv = tanhf(c2) * so;
  h[gid] = hv;
  if (hseq) hseq[(size_t)(t * BATCH + b) * HID + u] = hv;
}

// ---------------- naive f32 dense GEMM: out[r][n] = sum_k H[r][k]*Wd[k][n] + bd[n] ----
// grid dim3(125, 512): bx -> n-slice of 256, by -> 8-row group.
__global__ __launch_bounds__(256) void gemm_naive(
    const float* H, const float* Wd, const float* bd, float* out) {
  int n  = blockIdx.x * 256 + threadIdx.x;   // [0, 32000)
  int r0 = blockIdx.y * 8;
  float bv = bd[n];
  float acc[8];
#pragma unroll
  for (int i = 0; i < 8; ++i) acc[i] = bv;
  for (int k = 0; k < HID; ++k) {
    float wv = Wd[(size_t)k * VOCAB + n];
#pragma unroll
    for (int i = 0; i < 8; ++i) acc[i] += H[(size_t)(r0 + i) * HID + k] * wv;
  }
#pragma unroll
  for (int i = 0; i < 8; ++i) out[(size_t)(r0 + i) * VOCAB + n] = acc[i];
}

// ---------------- host ----------------
extern "C" void kernel_launch(void* const* d_in, const int* in_sizes, int n_in,
                              void* d_out, int out_size, void* d_ws, size_t ws_size,
                              hipStream_t stream) {
  const int*   ids = (const int*)d_in[0];
  const float* emb = (const float*)d_in[1];
  const float* W0  = (const float*)d_in[2];
  const float* b0  = (const float*)d_in[3];
  const float* W1  = (const float*)d_in[4];
  const float* b1  = (const float*)d_in[5];
  const float* Wd  = (const float*)d_in[6];
  const float* bd  = (const float*)d_in[7];
  float* out = (float*)d_out;

  char* ws = (char*)d_ws;
  size_t off = 0;
  auto alloc = [&](size_t bytes) {
    char* p = ws + off;
    off += (bytes + 255) & ~(size_t)255;
    return p;
  };
  int*   flag = (int*)alloc(256);
  float* h1   = (float*)alloc((size_t)BATCH * HID * 4);
  float* c1   = (float*)alloc((size_t)BATCH * HID * 4);
  float* h2   = (float*)alloc((size_t)BATCH * HID * 4);
  float* c2   = (float*)alloc((size_t)BATCH * HID * 4);
  float* z0b  = (float*)alloc((size_t)BATCH * G4 * 4);
  float* z1b  = (float*)alloc((size_t)BATCH * G4 * 4);
  float* H2f  = (float*)alloc((size_t)ROWS * HID * 4);   // 16.8 MB
  (void)in_sizes; (void)n_in; (void)out_size; (void)ws_size;

  hipMemsetAsync(h1, 0, (size_t)BATCH * HID * 4, stream);
  hipMemsetAsync(c1, 0, (size_t)BATCH * HID * 4, stream);
  hipMemsetAsync(h2, 0, (size_t)BATCH * HID * 4, stream);
  hipMemsetAsync(c2, 0, (size_t)BATCH * HID * 4, stream);

  detect_i64<<<1, 256, 0, stream>>>((const unsigned int*)ids, flag);

  for (int t = 0; t < SEQ; ++t) {
    z0_kernel<<<dim3(16, 32), 256, 0, stream>>>(ids, flag, emb, h1, W0, b0, z0b, t);
    gates_kernel<<<128, 256, 0, stream>>>(z0b, c1, h1, nullptr, t);
    z1_kernel<<<dim3(16, 32), 256, 0, stream>>>(h1, h2, W1, b1, z1b);
    gates_kernel<<<128, 256, 0, stream>>>(z1b, c2, h2, H2f, t);
  }

  gemm_naive<<<dim3(125, 512), 256, 0, stream>>>(H2f, Wd, bd, out);
}

// Round 5
// 22191.252 us; speedup vs baseline: 1.3765x; 1.3765x over previous
//
#include <hip/hip_runtime.h>

#define VOCAB 32000
#define EMB   1024
#define HID   1024
#define SEQ   128
#define BATCH 32
#define ROWS  (SEQ * BATCH)   // 4096
#define G4    (4 * HID)       // 4096

typedef __bf16 bf16x8 __attribute__((ext_vector_type(8)));
typedef float  f32x4  __attribute__((ext_vector_type(4)));

__device__ __forceinline__ unsigned short f2bf(float f) {
  union { float f; unsigned int u; } v; v.f = f;
  unsigned int r = v.u + 0x7fffu + ((v.u >> 16) & 1u);
  return (unsigned short)(r >> 16);
}

// ---------------- int64-vs-int32 input_seq detection ----------------
__global__ void detect_i64(const unsigned int* __restrict__ w, int* __restrict__ flag) {
  __shared__ unsigned int s[256];
  unsigned int v = 0;
  for (int i = threadIdx.x; i < 2048; i += 256) v |= w[2 * i + 1];
  s[threadIdx.x] = v;
  __syncthreads();
  if (threadIdx.x == 0) {
    unsigned int o = 0;
    for (int i = 0; i < 256; ++i) o |= s[i];
    *flag = (o == 0u) ? 1 : 0;
  }
}

// ---------------- layer-0 z: x gathered from embedding, all f32 ----------------
__global__ __launch_bounds__(256) void z0_kernel(
    const int* ids, const int* flag, const float* emb, const float* h,
    const float* W, const float* bvec, float* z, int t) {
  int n = blockIdx.x * 256 + threadIdx.x;   // [0, 4096)
  int b = blockIdx.y;                       // [0, 32)
  int r = t * BATCH + b;
  int tok = (*flag) ? ids[2 * r] : ids[r];
  const float* x  = emb + (size_t)tok * EMB;
  const float* hb = h + b * HID;
  float acc = bvec[n];
  for (int k = 0; k < EMB; ++k) acc += x[k]  * W[(size_t)k * G4 + n];
  for (int k = 0; k < HID; ++k) acc += hb[k] * W[(size_t)(EMB + k) * G4 + n];
  z[b * G4 + n] = acc;
}

// ---------------- layer-1 z: x = h1 (f32) ----------------
__global__ __launch_bounds__(256) void z1_kernel(
    const float* x, const float* h, const float* W, const float* bvec, float* z) {
  int n = blockIdx.x * 256 + threadIdx.x;
  int b = blockIdx.y;
  const float* xb = x + b * HID;
  const float* hb = h + b * HID;
  float acc = bvec[n];
  for (int k = 0; k < HID; ++k) acc += xb[k] * W[(size_t)k * G4 + n];
  for (int k = 0; k < HID; ++k) acc += hb[k] * W[(size_t)(HID + k) * G4 + n];
  z[b * G4 + n] = acc;
}

// ---------------- gates: z -> (c, h), optionally record h sequence ----------------
__global__ __launch_bounds__(256) void gates_kernel(
    const float* z, float* c, float* h, float* hseq, int t) {
  int gid = blockIdx.x * 256 + threadIdx.x;  // 32768 = 32*1024
  int b = gid >> 10, u = gid & 1023;
  float iv = z[b * G4 + u];
  float jv = z[b * G4 + 1024 + u];
  float fv = z[b * G4 + 2048 + u];
  float ov = z[b * G4 + 3072 + u];
  float si = 1.f / (1.f + expf(-iv));
  float sf = 1.f / (1.f + expf(-(fv + 1.f)));   // FORGET_BIAS = 1.0
  float so = 1.f / (1.f + expf(-ov));
  float tj = tanhf(jv);
  float c2 = c[gid] * sf + si * tj;
  c[gid] = c2;
  float hv = tanhf(c2) * so;
  h[gid] = hv;
  if (hseq) hseq[(size_t)(t * BATCH + b) * HID + u] = hv;
}

// ---------------- f32 -> bf16 convert (H2) ----------------
__global__ __launch_bounds__(256) void cvt_bf16(const float* __restrict__ in,
                                                unsigned short* __restrict__ out, int n4) {
  int i = blockIdx.x * 256 + threadIdx.x;   // one float4 per thread
  if (i >= n4) return;
  float4 v = *reinterpret_cast<const float4*>(in + (size_t)i * 4);
  ushort4 o;
  o.x = f2bf(v.x); o.y = f2bf(v.y); o.z = f2bf(v.z); o.w = f2bf(v.w);
  *reinterpret_cast<ushort4*>(out + (size_t)i * 4) = o;
}

// ---------------- transpose f32 [K][N] -> bf16 [N][K]  (verbatim r1-r3) ----------
__global__ void transpose_kernel(const float* __restrict__ in, unsigned short* __restrict__ out,
                                 int K, int N) {
  __shared__ float t[32][33];
  int n0 = blockIdx.x * 32, k0 = blockIdx.y * 32;
  int tx = threadIdx.x, ty = threadIdx.y;   // 32 x 8
#pragma unroll
  for (int i = 0; i < 4; ++i)
    t[ty + i * 8][tx] = in[(size_t)(k0 + ty + i * 8) * N + n0 + tx];
  __syncthreads();
#pragma unroll
  for (int i = 0; i < 4; ++i)
    out[(size_t)(n0 + ty + i * 8) * K + k0 + tx] = f2bf(t[tx][ty + i * 8]);
}

// ---------------- MFMA dense GEMM (verbatim r1-r3): C = A * B^T + bias ----------
__device__ __forceinline__ void async16(const void* g, void* l) {
  __builtin_amdgcn_global_load_lds(
      (const __attribute__((address_space(1))) void*)g,
      (__attribute__((address_space(3))) void*)l, 16, 0, 0);
}

__global__ __launch_bounds__(256) void gemm_bt(
    const unsigned short* __restrict__ A,    // [M][K] bf16
    const unsigned short* __restrict__ B,    // [N][K] bf16
    const float* __restrict__ bias,          // [N]
    float* __restrict__ C,                   // [M][N]
    int M, int N, int K)
{
  __shared__ __align__(16) unsigned short As[128 * 32];
  __shared__ __align__(16) unsigned short Bs[128 * 32];
  const int tid = threadIdx.x, lane = tid & 63, w = tid >> 6;

  const int ntiles = gridDim.x;
  int lid = blockIdx.y * ntiles + blockIdx.x;
  int total = ntiles * gridDim.y;
  int cpx = total >> 3;
  int swz = (lid & 7) * cpx + (lid >> 3);
  int bn = swz % ntiles, bm = swz / ntiles;

  const int wm = (w >> 1) * 64, wn = (w & 1) * 64;
  const int lrow = lane & 15, klo = (lane >> 4) * 8;
  const int l4 = lane >> 2, l2 = lane & 3;

  f32x4 acc[4][4] = {};

  for (int kt = 0; kt < K / 32; ++kt) {
    __syncthreads();
#pragma unroll
    for (int ci = 0; ci < 2; ++ci) {
      int row = w * 32 + ci * 16 + l4;
      async16(A + (size_t)(bm * 128 + row) * K + kt * 32 + l2 * 8,
              (char*)As + (w * 2 + ci) * 1024);
      async16(B + (size_t)(bn * 128 + row) * K + kt * 32 + l2 * 8,
              (char*)Bs + (w * 2 + ci) * 1024);
    }
    __syncthreads();
    bf16x8 a[4], b[4];
#pragma unroll
    for (int i = 0; i < 4; ++i) {
      a[i] = *reinterpret_cast<const bf16x8*>(As + (wm + i * 16 + lrow) * 32 + klo);
      b[i] = *reinterpret_cast<const bf16x8*>(Bs + (wn + i * 16 + lrow) * 32 + klo);
    }
#pragma unroll
    for (int i = 0; i < 4; ++i)
#pragma unroll
      for (int j = 0; j < 4; ++j)
        acc[i][j] = __builtin_amdgcn_mfma_f32_16x16x32_bf16(a[i], b[j], acc[i][j], 0, 0, 0);
  }

#pragma unroll
  for (int j2 = 0; j2 < 4; ++j2) {
    int col = bn * 128 + wn + j2 * 16 + lrow;
    float bv = bias[col];
#pragma unroll
    for (int i = 0; i < 4; ++i) {
      int rbase = bm * 128 + wm + i * 16 + (lane >> 4) * 4;
#pragma unroll
      for (int j = 0; j < 4; ++j)
        C[(size_t)(rbase + j) * N + col] = acc[i][j2][j] + bv;
    }
  }
}

// ---------------- host ----------------
extern "C" void kernel_launch(void* const* d_in, const int* in_sizes, int n_in,
                              void* d_out, int out_size, void* d_ws, size_t ws_size,
                              hipStream_t stream) {
  const int*   ids = (const int*)d_in[0];
  const float* emb = (const float*)d_in[1];
  const float* W0  = (const float*)d_in[2];
  const float* b0  = (const float*)d_in[3];
  const float* W1  = (const float*)d_in[4];
  const float* b1  = (const float*)d_in[5];
  const float* Wd  = (const float*)d_in[6];
  const float* bd  = (const float*)d_in[7];
  float* out = (float*)d_out;

  char* ws = (char*)d_ws;
  size_t off = 0;
  auto alloc = [&](size_t bytes) {
    char* p = ws + off;
    off += (bytes + 255) & ~(size_t)255;
    return p;
  };
  int*   flag = (int*)alloc(256);
  float* h1   = (float*)alloc((size_t)BATCH * HID * 4);
  float* c1   = (float*)alloc((size_t)BATCH * HID * 4);
  float* h2   = (float*)alloc((size_t)BATCH * HID * 4);
  float* c2   = (float*)alloc((size_t)BATCH * HID * 4);
  float* z0b  = (float*)alloc((size_t)BATCH * G4 * 4);
  float* z1b  = (float*)alloc((size_t)BATCH * G4 * 4);
  float* H2f  = (float*)alloc((size_t)ROWS * HID * 4);            // 16.8 MB
  unsigned short* H2b = (unsigned short*)alloc((size_t)ROWS * HID * 2);   //  8.4 MB
  unsigned short* Wdt = (unsigned short*)alloc((size_t)VOCAB * HID * 2);  // 65.5 MB
  (void)in_sizes; (void)n_in; (void)out_size; (void)ws_size;

  hipMemsetAsync(h1, 0, (size_t)BATCH * HID * 4, stream);
  hipMemsetAsync(c1, 0, (size_t)BATCH * HID * 4, stream);
  hipMemsetAsync(h2, 0, (size_t)BATCH * HID * 4, stream);
  hipMemsetAsync(c2, 0, (size_t)BATCH * HID * 4, stream);

  detect_i64<<<1, 256, 0, stream>>>((const unsigned int*)ids, flag);
  transpose_kernel<<<dim3(VOCAB / 32, HID / 32), dim3(32, 8), 0, stream>>>(Wd, Wdt, HID, VOCAB);

  for (int t = 0; t < SEQ; ++t) {
    z0_kernel<<<dim3(16, 32), 256, 0, stream>>>(ids, flag, emb, h1, W0, b0, z0b, t);
    gates_kernel<<<128, 256, 0, stream>>>(z0b, c1, h1, nullptr, t);
    z1_kernel<<<dim3(16, 32), 256, 0, stream>>>(h1, h2, W1, b1, z1b);
    gates_kernel<<<128, 256, 0, stream>>>(z1b, c2, h2, H2f, t);
  }

  cvt_bf16<<<(ROWS * HID / 4 + 255) / 256, 256, 0, stream>>>(H2f, H2b, ROWS * HID / 4);
  gemm_bt<<<dim3(VOCAB / 128, ROWS / 128), 256, 0, stream>>>(H2b, Wdt, bd, out, ROWS, VOCAB, HID);
}

// Round 6
// 12623.928 us; speedup vs baseline: 2.4197x; 1.7579x over previous
//
#include <hip/hip_runtime.h>
#include <hip/hip_cooperative_groups.h>

#define VOCAB 32000
#define EMB   1024
#define HID   1024
#define SEQ   128
#define BATCH 32
#define ROWS  (SEQ * BATCH)   // 4096
#define G4    (4 * HID)       // 4096

typedef __bf16 bf16x8 __attribute__((ext_vector_type(8)));
typedef float  f32x4  __attribute__((ext_vector_type(4)));

__device__ __forceinline__ unsigned short f2bf(float f) {
  union { float f; unsigned int u; } v; v.f = f;
  unsigned int r = v.u + 0x7fffu + ((v.u >> 16) & 1u);
  return (unsigned short)(r >> 16);
}

__device__ __forceinline__ void async16(const void* g, void* l) {
  __builtin_amdgcn_global_load_lds(
      (const __attribute__((address_space(1))) void*)g,
      (__attribute__((address_space(3))) void*)l, 16, 0, 0);
}

// ================= fused 2-layer LSTM recurrence, all-f32 (cooperative) ======
// blocks 0..127: layer 0 (step s computes t=s, s<128)
// blocks 128..255: layer 1 (step s computes t=s-1, s>=1)
// Per WG: 8 h-cols x 4 gates (32 z-cols), full K=2048, all 32 batches.
// h/x tile in padded LDS; W streamed from global (L3-resident) via
// global_load_lds 64kx32n f32 tiles, 3-buffer counted-vmcnt pipeline.
__global__ __launch_bounds__(256) void lstm_f32(
    const int* __restrict__ ids, const float* __restrict__ emb,
    const float* __restrict__ W0, const float* __restrict__ W1,
    const float* __restrict__ b0, const float* __restrict__ b1,
    float* __restrict__ H2f,      // [4096][1024] layer-1 h sequence
    float* __restrict__ h1buf,    // [2][32][1024]
    float* __restrict__ h2buf)    // [2][32][1024]
{
  cooperative_groups::grid_group grid = cooperative_groups::this_grid();
  __shared__ __align__(16) float hx[32 * 1028];       // 128.5 KB padded rows
  __shared__ __align__(16) float Wt3[3 * 64 * 32];    //  24 KB: 3 tiles [64k][32n]
  __shared__ __align__(16) float zl[32 * 36];         //   4.5 KB padded

  const int tid   = threadIdx.x;
  const int w     = tid >> 6;
  const int layer = blockIdx.x >> 7;
  const int wg    = blockIdx.x & 127;
  const int j0    = wg * 8;

  const float* Wm   = layer ? W1 : W0;
  const float* bias = layer ? b1 : b0;

  // compute mapping: lane batch b, n-group ng (gate=ng>>1, c4=ng&1)
  const int b  = tid & 31;
  const int ng = tid >> 5;
  // stage mapping: row srow, 128-float part
  const int srow = tid & 31, spart = tid >> 5;
  // elementwise mapping
  const int eb = tid >> 3, ec = tid & 7;
  const float bi = bias[j0 + ec], bj = bias[1024 + j0 + ec];
  const float bf_ = bias[2048 + j0 + ec], bo = bias[3072 + j0 + ec];
  float c = 0.f;

  for (int s = 0; s <= SEQ; ++s) {
    const bool active = layer ? (s >= 1) : (s < SEQ);
    if (active) {
      const int t  = layer ? (s - 1) : s;
      const int rb = s & 1;
      f32x4 zacc = {0.f, 0.f, 0.f, 0.f};

      for (int phase = 0; phase < 2; ++phase) {
        // ---- stage this phase's [32][1024] x/h block into padded LDS ----
        const float* srcrow;
        if (layer == 0 && phase == 0) {
          int tok = ids[t * 32 + srow];
          srcrow = emb + (size_t)tok * 1024;
        } else if (phase == 0) {
          srcrow = h1buf + rb * (32 * 1024) + srow * 1024;   // layer1 x = h1(t)
        } else {
          srcrow = (layer ? h2buf : h1buf) + rb * (32 * 1024) + srow * 1024;
        }
#pragma unroll 1
        for (int rd = 0; rd < 4; ++rd) {
          float4 v[8];
#pragma unroll
          for (int q = 0; q < 8; ++q)
            v[q] = *reinterpret_cast<const float4*>(srcrow + spart * 128 + rd * 32 + q * 4);
#pragma unroll
          for (int q = 0; q < 8; ++q)
            *reinterpret_cast<float4*>(&hx[srow * 1028 + spart * 128 + rd * 32 + q * 4]) = v[q];
        }

        // ---- W tile DMA: tile = [64 k][32 n], 2 global_load_lds per wave ----
        const int kbase = phase * 1024;
        auto stageW = [&](int tile) {
          int bufo = (tile % 3) * (64 * 32);
#pragma unroll
          for (int it = 0; it < 2; ++it) {
            int gb = it * 256 + w * 64;          // wave-uniform granule base
            int g  = gb + (tid & 63);            // this lane's granule
            int k  = kbase + tile * 64 + (g >> 3);
            int sub = g & 7;                     // (gate, c4)
            const float* src = Wm + (size_t)k * G4 + (sub >> 1) * 1024 + j0 + (sub & 1) * 4;
            async16(src, (char*)Wt3 + (size_t)(bufo + gb * 4) * 4);
          }
        };
        stageW(0); stageW(1);
        __syncthreads();   // hx ds_writes + W t0/t1 drained (vmcnt 0 at barrier)

        for (int tile = 0; tile < 16; ++tile) {
          if (tile >= 1) {
            asm volatile("s_waitcnt vmcnt(2)" ::: "memory");
            __builtin_amdgcn_s_barrier();
            __builtin_amdgcn_sched_barrier(0);
          }
          const int bufo = (tile % 3) * (64 * 32);
#pragma unroll 4
          for (int k4 = 0; k4 < 16; ++k4) {
            f32x4 h4 = *reinterpret_cast<const f32x4*>(&hx[b * 1028 + tile * 64 + k4 * 4]);
#pragma unroll
            for (int e = 0; e < 4; ++e) {
              f32x4 w4 = *reinterpret_cast<const f32x4*>(&Wt3[bufo + (k4 * 4 + e) * 32 + ng * 4]);
              zacc[0] += h4[e] * w4[0];
              zacc[1] += h4[e] * w4[1];
              zacc[2] += h4[e] * w4[2];
              zacc[3] += h4[e] * w4[3];
            }
          }
          if (tile + 2 < 16) { __builtin_amdgcn_s_barrier(); stageW(tile + 2); }
        }
        __syncthreads();   // phase done before hx overwrite / zl
      }

      // ---- exchange z and do the elementwise cell update ----
      *reinterpret_cast<f32x4*>(&zl[b * 36 + ng * 4]) = zacc;
      __syncthreads();
      float iv = bi  + zl[eb * 36 + ec];
      float jv = bj  + zl[eb * 36 + 8 + ec];
      float fv = bf_ + zl[eb * 36 + 16 + ec];
      float ov = bo  + zl[eb * 36 + 24 + ec];
      float si = 1.f / (1.f + expf(-iv));
      float sf = 1.f / (1.f + expf(-(fv + 1.f)));   // FORGET_BIAS = 1.0
      float so = 1.f / (1.f + expf(-ov));
      float tj = tanhf(jv);
      c = c * sf + si * tj;
      float hv = tanhf(c) * so;
      float* outBuf = (layer ? h2buf : h1buf) + ((s + 1) & 1) * (32 * 1024);
      outBuf[eb * 1024 + j0 + ec] = hv;
      if (layer) H2f[(size_t)(t * 32 + eb) * 1024 + j0 + ec] = hv;
      __syncthreads();   // zl reads done before next step reuses it
    }
    grid.sync();
  }
}

// ================= projection: validated r5 path ============================
__global__ __launch_bounds__(256) void cvt_bf16(const float* __restrict__ in,
                                                unsigned short* __restrict__ out, int n4) {
  int i = blockIdx.x * 256 + threadIdx.x;
  if (i >= n4) return;
  float4 v = *reinterpret_cast<const float4*>(in + (size_t)i * 4);
  ushort4 o;
  o.x = f2bf(v.x); o.y = f2bf(v.y); o.z = f2bf(v.z); o.w = f2bf(v.w);
  *reinterpret_cast<ushort4*>(out + (size_t)i * 4) = o;
}

__global__ void transpose_kernel(const float* __restrict__ in, unsigned short* __restrict__ out,
                                 int K, int N) {
  __shared__ float t[32][33];
  int n0 = blockIdx.x * 32, k0 = blockIdx.y * 32;
  int tx = threadIdx.x, ty = threadIdx.y;   // 32 x 8
#pragma unroll
  for (int i = 0; i < 4; ++i)
    t[ty + i * 8][tx] = in[(size_t)(k0 + ty + i * 8) * N + n0 + tx];
  __syncthreads();
#pragma unroll
  for (int i = 0; i < 4; ++i)
    out[(size_t)(n0 + ty + i * 8) * K + k0 + tx] = f2bf(t[tx][ty + i * 8]);
}

__global__ __launch_bounds__(256) void gemm_bt(
    const unsigned short* __restrict__ A,    // [M][K] bf16
    const unsigned short* __restrict__ B,    // [N][K] bf16
    const float* __restrict__ bias,          // [N]
    float* __restrict__ C,                   // [M][N]
    int M, int N, int K)
{
  __shared__ __align__(16) unsigned short As[128 * 32];
  __shared__ __align__(16) unsigned short Bs[128 * 32];
  const int tid = threadIdx.x, lane = tid & 63, w = tid >> 6;

  const int ntiles = gridDim.x;
  int lid = blockIdx.y * ntiles + blockIdx.x;
  int total = ntiles * gridDim.y;
  int cpx = total >> 3;
  int swz = (lid & 7) * cpx + (lid >> 3);
  int bn = swz % ntiles, bm = swz / ntiles;

  const int wm = (w >> 1) * 64, wn = (w & 1) * 64;
  const int lrow = lane & 15, klo = (lane >> 4) * 8;
  const int l4 = lane >> 2, l2 = lane & 3;

  f32x4 acc[4][4] = {};

  for (int kt = 0; kt < K / 32; ++kt) {
    __syncthreads();
#pragma unroll
    for (int ci = 0; ci < 2; ++ci) {
      int row = w * 32 + ci * 16 + l4;
      async16(A + (size_t)(bm * 128 + row) * K + kt * 32 + l2 * 8,
              (char*)As + (w * 2 + ci) * 1024);
      async16(B + (size_t)(bn * 128 + row) * K + kt * 32 + l2 * 8,
              (char*)Bs + (w * 2 + ci) * 1024);
    }
    __syncthreads();
    bf16x8 a[4], bb[4];
#pragma unroll
    for (int i = 0; i < 4; ++i) {
      a[i]  = *reinterpret_cast<const bf16x8*>(As + (wm + i * 16 + lrow) * 32 + klo);
      bb[i] = *reinterpret_cast<const bf16x8*>(Bs + (wn + i * 16 + lrow) * 32 + klo);
    }
#pragma unroll
    for (int i = 0; i < 4; ++i)
#pragma unroll
      for (int j = 0; j < 4; ++j)
        acc[i][j] = __builtin_amdgcn_mfma_f32_16x16x32_bf16(a[i], bb[j], acc[i][j], 0, 0, 0);
  }

#pragma unroll
  for (int j2 = 0; j2 < 4; ++j2) {
    int col = bn * 128 + wn + j2 * 16 + lrow;
    float bv = bias[col];
#pragma unroll
    for (int i = 0; i < 4; ++i) {
      int rbase = bm * 128 + wm + i * 16 + (lane >> 4) * 4;
#pragma unroll
      for (int j = 0; j < 4; ++j)
        C[(size_t)(rbase + j) * N + col] = acc[i][j2][j] + bv;
    }
  }
}

// ================= host =====================================================
extern "C" void kernel_launch(void* const* d_in, const int* in_sizes, int n_in,
                              void* d_out, int out_size, void* d_ws, size_t ws_size,
                              hipStream_t stream) {
  const int*   ids = (const int*)d_in[0];
  const float* emb = (const float*)d_in[1];
  const float* W0  = (const float*)d_in[2];
  const float* b0  = (const float*)d_in[3];
  const float* W1  = (const float*)d_in[4];
  const float* b1  = (const float*)d_in[5];
  const float* Wd  = (const float*)d_in[6];
  const float* bd  = (const float*)d_in[7];
  float* out = (float*)d_out;

  char* ws = (char*)d_ws;
  size_t off = 0;
  auto alloc = [&](size_t bytes) {
    char* p = ws + off;
    off += (bytes + 255) & ~(size_t)255;
    return p;
  };
  float* h1b = (float*)alloc((size_t)2 * BATCH * HID * 4);               // 256 KB
  float* h2b = (float*)alloc((size_t)2 * BATCH * HID * 4);               // 256 KB
  float* H2f = (float*)alloc((size_t)ROWS * HID * 4);                    // 16.8 MB
  unsigned short* H2bq = (unsigned short*)alloc((size_t)ROWS * HID * 2); //  8.4 MB
  unsigned short* Wdt  = (unsigned short*)alloc((size_t)VOCAB * HID * 2);// 65.5 MB
  (void)in_sizes; (void)n_in; (void)out_size; (void)ws_size;

  hipMemsetAsync(h1b, 0, (size_t)2 * BATCH * HID * 4, stream);
  hipMemsetAsync(h2b, 0, (size_t)2 * BATCH * HID * 4, stream);

  transpose_kernel<<<dim3(VOCAB / 32, HID / 32), dim3(32, 8), 0, stream>>>(Wd, Wdt, HID, VOCAB);

  void* args[] = {(void*)&ids, (void*)&emb, (void*)&W0, (void*)&W1,
                  (void*)&b0, (void*)&b1, (void*)&H2f, (void*)&h1b, (void*)&h2b};
  hipLaunchCooperativeKernel((void*)lstm_f32, dim3(256), dim3(256), args, 0, stream);

  cvt_bf16<<<(ROWS * HID / 4 + 255) / 256, 256, 0, stream>>>(H2f, H2bq, ROWS * HID / 4);
  gemm_bt<<<dim3(VOCAB / 128, ROWS / 128), 256, 0, stream>>>(H2bq, Wdt, bd, out, ROWS, VOCAB, HID);
}

// Round 8
// 5225.624 us; speedup vs baseline: 5.8454x; 2.4158x over previous
//
#include <hip/hip_runtime.h>
#include <hip/hip_cooperative_groups.h>

#define VOCAB 32000
#define EMB   1024
#define HID   1024
#define SEQ   128
#define BATCH 32
#define ROWS  (SEQ * BATCH)   // 4096
#define G4    (4 * HID)       // 4096

typedef __bf16 bf16x8 __attribute__((ext_vector_type(8)));
typedef float  f32x4  __attribute__((ext_vector_type(4)));

__device__ __forceinline__ unsigned short f2bf(float f) {
  union { float f; unsigned int u; } v; v.f = f;
  unsigned int r = v.u + 0x7fffu + ((v.u >> 16) & 1u);
  return (unsigned short)(r >> 16);
}
__device__ __forceinline__ float bf2f(unsigned short u) {
  union { unsigned int u; float f; } v; v.u = ((unsigned int)u) << 16;
  return v.f;
}

__device__ __forceinline__ void async16(const void* g, void* l) {
  __builtin_amdgcn_global_load_lds(
      (const __attribute__((address_space(1))) void*)g,
      (__attribute__((address_space(3))) void*)l, 16, 0, 0);
}

// ---------------- embedding gather + f32 -> (bf16 hi, bf16 lo) ----------------
__global__ void embed_split(const int* __restrict__ ids, const float* __restrict__ emb,
                            unsigned short* __restrict__ Xhi, unsigned short* __restrict__ Xlo) {
  int r = blockIdx.x;                 // 0..4095 = t*32+b
  int row = ids[r];
  int e = threadIdx.x * 4;
  const float4 v = *reinterpret_cast<const float4*>(emb + (size_t)row * EMB + e);
  ushort4 hi, lo;
  hi.x = f2bf(v.x); lo.x = f2bf(v.x - bf2f(hi.x));
  hi.y = f2bf(v.y); lo.y = f2bf(v.y - bf2f(hi.y));
  hi.z = f2bf(v.z); lo.z = f2bf(v.z - bf2f(hi.z));
  hi.w = f2bf(v.w); lo.w = f2bf(v.w - bf2f(hi.w));
  *reinterpret_cast<ushort4*>(Xhi + (size_t)r * EMB + e) = hi;
  *reinterpret_cast<ushort4*>(Xlo + (size_t)r * EMB + e) = lo;
}

// ------------- transpose+split f32 [K][N] -> bf16 hi/lo [N][K] -------------
__global__ void wsplit_kernel(const float* __restrict__ in, unsigned short* __restrict__ hi,
                              unsigned short* __restrict__ lo, int K, int N) {
  __shared__ float t[32][33];
  int n0 = blockIdx.x * 32, k0 = blockIdx.y * 32;
  int tx = threadIdx.x, ty = threadIdx.y;   // 32 x 8
#pragma unroll
  for (int i = 0; i < 4; ++i)
    t[ty + i * 8][tx] = in[(size_t)(k0 + ty + i * 8) * N + n0 + tx];
  __syncthreads();
#pragma unroll
  for (int i = 0; i < 4; ++i) {
    float v = t[tx][ty + i * 8];
    unsigned short h = f2bf(v);
    hi[(size_t)(n0 + ty + i * 8) * K + k0 + tx] = h;
    lo[(size_t)(n0 + ty + i * 8) * K + k0 + tx] = f2bf(v - bf2f(h));
  }
}

// ------------- transpose f32 [K][N] -> bf16 [N][K] (Wd, r5-validated) -------
__global__ void transpose_kernel(const float* __restrict__ in, unsigned short* __restrict__ out,
                                 int K, int N) {
  __shared__ float t[32][33];
  int n0 = blockIdx.x * 32, k0 = blockIdx.y * 32;
  int tx = threadIdx.x, ty = threadIdx.y;   // 32 x 8
#pragma unroll
  for (int i = 0; i < 4; ++i)
    t[ty + i * 8][tx] = in[(size_t)(k0 + ty + i * 8) * N + n0 + tx];
  __syncthreads();
#pragma unroll
  for (int i = 0; i < 4; ++i)
    out[(size_t)(n0 + ty + i * 8) * K + k0 + tx] = f2bf(t[tx][ty + i * 8]);
}

// ============ fused 2-layer LSTM: register-resident split-bf16 W, MFMA z-path,
// f32 cell state. 256 blocks x 512 threads (8 waves, K=256 each).
// blocks 0..127 layer0 (t=s), 128..255 layer1 (t=s-1).
__global__ __launch_bounds__(512, 2) void lstm_mfma8(
    const unsigned short* __restrict__ Xhi, const unsigned short* __restrict__ Xlo,
    const unsigned short* __restrict__ W0hi, const unsigned short* __restrict__ W0lo,
    const unsigned short* __restrict__ W1hi, const unsigned short* __restrict__ W1lo,
    const float* __restrict__ b0, const float* __restrict__ b1,
    unsigned short* __restrict__ H2,         // [4096][1024] bf16
    unsigned short* h1hi, unsigned short* h1lo,   // [2][32][1024] bf16 each
    unsigned short* h2hi, unsigned short* h2lo)
{
  cooperative_groups::grid_group grid = cooperative_groups::this_grid();
  __shared__ float zl[8][32][32];            // 32 KB per-wave K-partials

  const int tid   = threadIdx.x;
  const int lane  = tid & 63;
  const int w     = tid >> 6;                // wave 0..7, K-range w*256..+256
  const int layer = blockIdx.x >> 7;
  const int wg    = blockIdx.x & 127;
  const int j0    = wg * 8;                  // 8 h-cols per WG
  const int lrow  = lane & 15;
  const int klo   = (lane >> 4) * 8;

  const unsigned short* Whi = layer ? W1hi : W0hi;
  const unsigned short* Wlo = layer ? W1lo : W0lo;
  const float*          bias = layer ? b1 : b0;

  // ---- zero h state: 4 arrays x 32768 uints = 131072 uints, 131072 threads ----
  {
    int idx = blockIdx.x * 512 + tid;
    if      (idx < 32768)  ((unsigned int*)h1hi)[idx] = 0u;
    else if (idx < 65536)  ((unsigned int*)h1lo)[idx - 32768] = 0u;
    else if (idx < 98304)  ((unsigned int*)h2hi)[idx - 65536] = 0u;
    else                   ((unsigned int*)h2lo)[idx - 98304] = 0u;
  }

  // ---- persistent W fragments (hi+lo, 128 VGPRs) ----
  // B-frag: lane holds n = nt*16+lrow, k = klo..klo+8 within each 32-k slice.
  // W^T [4096 n][2048 k]; local n <-> global row (n>>3)*1024 + j0 + (n&7)
  bf16x8 wh[2][8], wl[2][8];
#pragma unroll
  for (int nt = 0; nt < 2; ++nt) {
    int n = nt * 16 + lrow;
    size_t grow = (size_t)((n >> 3) * 1024 + j0 + (n & 7));
    const unsigned short* bh = Whi + grow * 2048 + w * 256 + klo;
    const unsigned short* bl = Wlo + grow * 2048 + w * 256 + klo;
#pragma unroll
    for (int ks = 0; ks < 8; ++ks) {
      wh[nt][ks] = *reinterpret_cast<const bf16x8*>(bh + ks * 32);
      wl[nt][ks] = *reinterpret_cast<const bf16x8*>(bl + ks * 32);
    }
  }

  // elementwise ownership (tid<256): thread -> (batch eb, hcol ec)
  const int eb = tid >> 3;
  const int ec = tid & 7;
  const float bi  = bias[j0 + ec];
  const float bj  = bias[1024 + j0 + ec];
  const float bff = bias[2048 + j0 + ec];
  const float bo  = bias[3072 + j0 + ec];
  float c = 0.f;

  grid.sync();   // h-zero visible everywhere

  for (int s = 0; s <= SEQ; ++s) {
    const bool active = layer ? (s >= 1) : (s < SEQ);
    if (active) {
      const int t  = layer ? (s - 1) : s;
      const int rb = s & 1;

      // A sources: waves 0-3 cover the x-half (K 0..1024), 4-7 the h-half
      const unsigned short *aHi, *aLo;
      if (layer == 0) {
        if (w < 4) { aHi = Xhi + (size_t)t * 32 * 1024; aLo = Xlo + (size_t)t * 32 * 1024; }
        else       { aHi = h1hi + rb * 32768;           aLo = h1lo + rb * 32768; }
      } else {
        if (w < 4) { aHi = h1hi + rb * 32768;           aLo = h1lo + rb * 32768; }
        else       { aHi = h2hi + rb * 32768;           aLo = h2lo + rb * 32768; }
      }
      const int aoff = (w & 3) * 256;
      const unsigned short* aH0 = aHi + (size_t)lrow * 1024 + aoff + klo;
      const unsigned short* aL0 = aLo + (size_t)lrow * 1024 + aoff + klo;
      const unsigned short* aH1 = aH0 + 16 * 1024;
      const unsigned short* aL1 = aL0 + 16 * 1024;

      f32x4 acc[2][2] = {};
#pragma unroll
      for (int ks = 0; ks < 8; ++ks) {
        bf16x8 a0h = *reinterpret_cast<const bf16x8*>(aH0 + ks * 32);
        bf16x8 a0l = *reinterpret_cast<const bf16x8*>(aL0 + ks * 32);
        bf16x8 a1h = *reinterpret_cast<const bf16x8*>(aH1 + ks * 32);
        bf16x8 a1l = *reinterpret_cast<const bf16x8*>(aL1 + ks * 32);
#pragma unroll
        for (int nt = 0; nt < 2; ++nt) {
          acc[0][nt] = __builtin_amdgcn_mfma_f32_16x16x32_bf16(a0h, wh[nt][ks], acc[0][nt], 0, 0, 0);
          acc[0][nt] = __builtin_amdgcn_mfma_f32_16x16x32_bf16(a0l, wh[nt][ks], acc[0][nt], 0, 0, 0);
          acc[0][nt] = __builtin_amdgcn_mfma_f32_16x16x32_bf16(a0h, wl[nt][ks], acc[0][nt], 0, 0, 0);
          acc[1][nt] = __builtin_amdgcn_mfma_f32_16x16x32_bf16(a1h, wh[nt][ks], acc[1][nt], 0, 0, 0);
          acc[1][nt] = __builtin_amdgcn_mfma_f32_16x16x32_bf16(a1l, wh[nt][ks], acc[1][nt], 0, 0, 0);
          acc[1][nt] = __builtin_amdgcn_mfma_f32_16x16x32_bf16(a1h, wl[nt][ks], acc[1][nt], 0, 0, 0);
        }
      }

      // C/D (r5-validated): col = lane&15 (n), row = (lane>>4)*4 + j (batch)
      const int zb = (lane >> 4) * 4;
#pragma unroll
      for (int mt = 0; mt < 2; ++mt)
#pragma unroll
        for (int nt = 0; nt < 2; ++nt)
#pragma unroll
          for (int j = 0; j < 4; ++j)
            zl[w][mt * 16 + zb + j][nt * 16 + lrow] = acc[mt][nt][j];
      __syncthreads();

      if (tid < 256) {
        float iv = bi, jv = bj, fv = bff, ov = bo;
#pragma unroll
        for (int ww = 0; ww < 8; ++ww) {
          iv += zl[ww][eb][ec];
          jv += zl[ww][eb][8 + ec];
          fv += zl[ww][eb][16 + ec];
          ov += zl[ww][eb][24 + ec];
        }
        float si = 1.f / (1.f + expf(-iv));
        float sf = 1.f / (1.f + expf(-(fv + 1.f)));   // FORGET_BIAS = 1.0
        float so = 1.f / (1.f + expf(-ov));
        float tj = tanhf(jv);
        c = c * sf + si * tj;
        float hv = tanhf(c) * so;
        unsigned short hh = f2bf(hv);
        unsigned short hl = f2bf(hv - bf2f(hh));
        const int wb = (s + 1) & 1;
        (layer ? h2hi : h1hi)[wb * 32768 + eb * 1024 + j0 + ec] = hh;
        (layer ? h2lo : h1lo)[wb * 32768 + eb * 1024 + j0 + ec] = hl;
        if (layer) H2[(size_t)(t * 32 + eb) * 1024 + j0 + ec] = hh;
      }
      __syncthreads();   // zl reads done before next step's overwrite
    }
    grid.sync();
  }
}

// ============ FALLBACK: r6-validated all-f32 recurrence =====================
__global__ __launch_bounds__(256) void lstm_f32(
    const int* __restrict__ ids, const float* __restrict__ emb,
    const float* __restrict__ W0, const float* __restrict__ W1,
    const float* __restrict__ b0, const float* __restrict__ b1,
    float* __restrict__ H2f, float* __restrict__ h1buf, float* __restrict__ h2buf)
{
  cooperative_groups::grid_group grid = cooperative_groups::this_grid();
  __shared__ __align__(16) float hx[32 * 1028];
  __shared__ __align__(16) float Wt3[3 * 64 * 32];
  __shared__ __align__(16) float zl[32 * 36];

  const int tid   = threadIdx.x;
  const int w     = tid >> 6;
  const int layer = blockIdx.x >> 7;
  const int wg    = blockIdx.x & 127;
  const int j0    = wg * 8;

  const float* Wm   = layer ? W1 : W0;
  const float* bias = layer ? b1 : b0;

  const int b  = tid & 31;
  const int ng = tid >> 5;
  const int srow = tid & 31, spart = tid >> 5;
  const int eb = tid >> 3, ec = tid & 7;
  const float bi = bias[j0 + ec], bj = bias[1024 + j0 + ec];
  const float bf_ = bias[2048 + j0 + ec], bo = bias[3072 + j0 + ec];
  float c = 0.f;

  for (int s = 0; s <= SEQ; ++s) {
    const bool active = layer ? (s >= 1) : (s < SEQ);
    if (active) {
      const int t  = layer ? (s - 1) : s;
      const int rb = s & 1;
      f32x4 zacc = {0.f, 0.f, 0.f, 0.f};

      for (int phase = 0; phase < 2; ++phase) {
        const float* srcrow;
        if (layer == 0 && phase == 0) {
          int tok = ids[t * 32 + srow];
          srcrow = emb + (size_t)tok * 1024;
        } else if (phase == 0) {
          srcrow = h1buf + rb * (32 * 1024) + srow * 1024;
        } else {
          srcrow = (layer ? h2buf : h1buf) + rb * (32 * 1024) + srow * 1024;
        }
#pragma unroll 1
        for (int rd = 0; rd < 4; ++rd) {
          float4 v[8];
#pragma unroll
          for (int q = 0; q < 8; ++q)
            v[q] = *reinterpret_cast<const float4*>(srcrow + spart * 128 + rd * 32 + q * 4);
#pragma unroll
          for (int q = 0; q < 8; ++q)
            *reinterpret_cast<float4*>(&hx[srow * 1028 + spart * 128 + rd * 32 + q * 4]) = v[q];
        }

        const int kbase = phase * 1024;
        auto stageW = [&](int tile) {
          int bufo = (tile % 3) * (64 * 32);
#pragma unroll
          for (int it = 0; it < 2; ++it) {
            int gb = it * 256 + w * 64;
            int g  = gb + (tid & 63);
            int k  = kbase + tile * 64 + (g >> 3);
            int sub = g & 7;
            const float* src = Wm + (size_t)k * G4 + (sub >> 1) * 1024 + j0 + (sub & 1) * 4;
            async16(src, (char*)Wt3 + (size_t)(bufo + gb * 4) * 4);
          }
        };
        stageW(0); stageW(1);
        __syncthreads();

        for (int tile = 0; tile < 16; ++tile) {
          if (tile >= 1) {
            asm volatile("s_waitcnt vmcnt(2)" ::: "memory");
            __builtin_amdgcn_s_barrier();
            __builtin_amdgcn_sched_barrier(0);
          }
          const int bufo = (tile % 3) * (64 * 32);
#pragma unroll 4
          for (int k4 = 0; k4 < 16; ++k4) {
            f32x4 h4 = *reinterpret_cast<const f32x4*>(&hx[b * 1028 + tile * 64 + k4 * 4]);
#pragma unroll
            for (int e = 0; e < 4; ++e) {
              f32x4 w4 = *reinterpret_cast<const f32x4*>(&Wt3[bufo + (k4 * 4 + e) * 32 + ng * 4]);
              zacc[0] += h4[e] * w4[0];
              zacc[1] += h4[e] * w4[1];
              zacc[2] += h4[e] * w4[2];
              zacc[3] += h4[e] * w4[3];
            }
          }
          if (tile + 2 < 16) { __builtin_amdgcn_s_barrier(); stageW(tile + 2); }
        }
        __syncthreads();
      }

      *reinterpret_cast<f32x4*>(&zl[b * 36 + ng * 4]) = zacc;
      __syncthreads();
      float iv = bi  + zl[eb * 36 + ec];
      float jv = bj  + zl[eb * 36 + 8 + ec];
      float fv = bf_ + zl[eb * 36 + 16 + ec];
      float ov = bo  + zl[eb * 36 + 24 + ec];
      float si = 1.f / (1.f + expf(-iv));
      float sf = 1.f / (1.f + expf(-(fv + 1.f)));
      float so = 1.f / (1.f + expf(-ov));
      float tj = tanhf(jv);
      c = c * sf + si * tj;
      float hv = tanhf(c) * so;
      float* outBuf = (layer ? h2buf : h1buf) + ((s + 1) & 1) * (32 * 1024);
      outBuf[eb * 1024 + j0 + ec] = hv;
      if (layer) H2f[(size_t)(t * 32 + eb) * 1024 + j0 + ec] = hv;
      __syncthreads();
    }
    grid.sync();
  }
}

__global__ __launch_bounds__(256) void cvt_bf16(const float* __restrict__ in,
                                                unsigned short* __restrict__ out, int n4) {
  int i = blockIdx.x * 256 + threadIdx.x;
  if (i >= n4) return;
  float4 v = *reinterpret_cast<const float4*>(in + (size_t)i * 4);
  ushort4 o;
  o.x = f2bf(v.x); o.y = f2bf(v.y); o.z = f2bf(v.z); o.w = f2bf(v.w);
  *reinterpret_cast<ushort4*>(out + (size_t)i * 4) = o;
}

// ---------------- MFMA dense GEMM (r5-validated): C = A * B^T + bias ----------
__global__ __launch_bounds__(256) void gemm_bt(
    const unsigned short* __restrict__ A, const unsigned short* __restrict__ B,
    const float* __restrict__ bias, float* __restrict__ C, int M, int N, int K)
{
  __shared__ __align__(16) unsigned short As[128 * 32];
  __shared__ __align__(16) unsigned short Bs[128 * 32];
  const int tid = threadIdx.x, lane = tid & 63, w = tid >> 6;

  const int ntiles = gridDim.x;
  int lid = blockIdx.y * ntiles + blockIdx.x;
  int total = ntiles * gridDim.y;
  int cpx = total >> 3;
  int swz = (lid & 7) * cpx + (lid >> 3);
  int bn = swz % ntiles, bm = swz / ntiles;

  const int wm = (w >> 1) * 64, wn = (w & 1) * 64;
  const int lrow = lane & 15, klo = (lane >> 4) * 8;
  const int l4 = lane >> 2, l2 = lane & 3;

  f32x4 acc[4][4] = {};

  for (int kt = 0; kt < K / 32; ++kt) {
    __syncthreads();
#pragma unroll
    for (int ci = 0; ci < 2; ++ci) {
      int row = w * 32 + ci * 16 + l4;
      async16(A + (size_t)(bm * 128 + row) * K + kt * 32 + l2 * 8,
              (char*)As + (w * 2 + ci) * 1024);
      async16(B + (size_t)(bn * 128 + row) * K + kt * 32 + l2 * 8,
              (char*)Bs + (w * 2 + ci) * 1024);
    }
    __syncthreads();
    bf16x8 a[4], bb[4];
#pragma unroll
    for (int i = 0; i < 4; ++i) {
      a[i]  = *reinterpret_cast<const bf16x8*>(As + (wm + i * 16 + lrow) * 32 + klo);
      bb[i] = *reinterpret_cast<const bf16x8*>(Bs + (wn + i * 16 + lrow) * 32 + klo);
    }
#pragma unroll
    for (int i = 0; i < 4; ++i)
#pragma unroll
      for (int j = 0; j < 4; ++j)
        acc[i][j] = __builtin_amdgcn_mfma_f32_16x16x32_bf16(a[i], bb[j], acc[i][j], 0, 0, 0);
  }

#pragma unroll
  for (int j2 = 0; j2 < 4; ++j2) {
    int col = bn * 128 + wn + j2 * 16 + lrow;
    float bv = bias[col];
#pragma unroll
    for (int i = 0; i < 4; ++i) {
      int rbase = bm * 128 + wm + i * 16 + (lane >> 4) * 4;
#pragma unroll
      for (int j = 0; j < 4; ++j)
        C[(size_t)(rbase + j) * N + col] = acc[i][j2][j] + bv;
    }
  }
}

// ================= host =====================================================
extern "C" void kernel_launch(void* const* d_in, const int* in_sizes, int n_in,
                              void* d_out, int out_size, void* d_ws, size_t ws_size,
                              hipStream_t stream) {
  const int*   ids = (const int*)d_in[0];
  const float* emb = (const float*)d_in[1];
  const float* W0  = (const float*)d_in[2];
  const float* b0  = (const float*)d_in[3];
  const float* W1  = (const float*)d_in[4];
  const float* b1  = (const float*)d_in[5];
  const float* Wd  = (const float*)d_in[6];
  const float* bd  = (const float*)d_in[7];
  float* out = (float*)d_out;

  // X hi/lo live in d_out (dead until gemm fully overwrites it): 16.8 MB of 524 MB
  unsigned short* Xhi = (unsigned short*)d_out;
  unsigned short* Xlo = Xhi + (size_t)ROWS * EMB;

  char* ws = (char*)d_ws;
  size_t off = 0;
  auto alloc = [&](size_t bytes) {
    char* p = ws + off;
    off += (bytes + 255) & ~(size_t)255;
    return p;
  };
  unsigned short* h1hi = (unsigned short*)alloc((size_t)2 * BATCH * HID * 2);
  unsigned short* h1lo = (unsigned short*)alloc((size_t)2 * BATCH * HID * 2);
  unsigned short* h2hi = (unsigned short*)alloc((size_t)2 * BATCH * HID * 2);
  unsigned short* h2lo = (unsigned short*)alloc((size_t)2 * BATCH * HID * 2);
  float* fh1 = (float*)alloc((size_t)2 * BATCH * HID * 4);   // fallback f32 h
  float* fh2 = (float*)alloc((size_t)2 * BATCH * HID * 4);
  unsigned short* H2 = (unsigned short*)alloc((size_t)ROWS * HID * 2);    //  8.4 MB
  size_t regionW = off;
  unsigned short* W0hi = (unsigned short*)alloc((size_t)G4 * 2048 * 2);   // 16.8 MB
  unsigned short* W0lo = (unsigned short*)alloc((size_t)G4 * 2048 * 2);   // 16.8 MB
  unsigned short* W1hi = (unsigned short*)alloc((size_t)G4 * 2048 * 2);   // 16.8 MB
  unsigned short* W1lo = (unsigned short*)alloc((size_t)G4 * 2048 * 2);   // 16.8 MB
  // aliases (dead-region reuse): Wdt over W-splits post-recurrence; H2f over W1lo (fallback only)
  unsigned short* Wdt = (unsigned short*)(ws + regionW);
  float*          H2f = (float*)W1lo;
  (void)in_sizes; (void)n_in; (void)out_size; (void)ws_size;   // total ws ~77 MB

  embed_split<<<ROWS, 256, 0, stream>>>(ids, emb, Xhi, Xlo);
  wsplit_kernel<<<dim3(G4 / 32, 2048 / 32), dim3(32, 8), 0, stream>>>(W0, W0hi, W0lo, 2048, G4);
  wsplit_kernel<<<dim3(G4 / 32, 2048 / 32), dim3(32, 8), 0, stream>>>(W1, W1hi, W1lo, 2048, G4);

  void* args[] = {(void*)&Xhi, (void*)&Xlo, (void*)&W0hi, (void*)&W0lo,
                  (void*)&W1hi, (void*)&W1lo, (void*)&b0, (void*)&b1,
                  (void*)&H2, (void*)&h1hi, (void*)&h1lo, (void*)&h2hi, (void*)&h2lo};
  hipError_t rc = hipLaunchCooperativeKernel((void*)lstm_mfma8, dim3(256), dim3(512),
                                             args, 0, stream);
  if (rc != hipSuccess) {
    // fallback: r6-validated f32 recurrence (reads raw W0/W1; W-splits unused)
    hipMemsetAsync(fh1, 0, (size_t)2 * BATCH * HID * 4, stream);
    hipMemsetAsync(fh2, 0, (size_t)2 * BATCH * HID * 4, stream);
    void* fargs[] = {(void*)&ids, (void*)&emb, (void*)&W0, (void*)&W1,
                     (void*)&b0, (void*)&b1, (void*)&H2f, (void*)&fh1, (void*)&fh2};
    hipLaunchCooperativeKernel((void*)lstm_f32, dim3(256), dim3(256), fargs, 0, stream);
    cvt_bf16<<<(ROWS * HID / 4 + 255) / 256, 256, 0, stream>>>(H2f, H2, ROWS * HID / 4);
  }

  transpose_kernel<<<dim3(VOCAB / 32, HID / 32), dim3(32, 8), 0, stream>>>(Wd, Wdt, HID, VOCAB);
  gemm_bt<<<dim3(VOCAB / 128, ROWS / 128), 256, 0, stream>>>(H2, Wdt, bd, out, ROWS, VOCAB, HID);
}

// Round 9
// 2151.556 us; speedup vs baseline: 14.1972x; 2.4288x over previous
//
#include <hip/hip_runtime.h>

#define VOCAB 32000
#define EMB   1024
#define HID   1024
#define SEQ   128
#define BATCH 32
#define ROWS  (SEQ * BATCH)   // 4096
#define G4    (4 * HID)       // 4096
#define LSLOT 32768           // ushorts per ring slot (32 rows x 1024)

typedef __bf16 bf16x8 __attribute__((ext_vector_type(8)));
typedef float  f32x4  __attribute__((ext_vector_type(4)));

__device__ __forceinline__ unsigned short f2bf(float f) {
  union { float f; unsigned int u; } v; v.f = f;
  unsigned int r = v.u + 0x7fffu + ((v.u >> 16) & 1u);
  return (unsigned short)(r >> 16);
}
__device__ __forceinline__ float bf2f(unsigned short u) {
  union { unsigned int u; float f; } v; v.u = ((unsigned int)u) << 16;
  return v.f;
}

__device__ __forceinline__ void async16(const void* g, void* l) {
  __builtin_amdgcn_global_load_lds(
      (const __attribute__((address_space(1))) void*)g,
      (__attribute__((address_space(3))) void*)l, 16, 0, 0);
}

// ---------------- embedding gather + f32 -> (bf16 hi, bf16 lo) ----------------
__global__ void embed_split(const int* __restrict__ ids, const float* __restrict__ emb,
                            unsigned short* __restrict__ Xhi, unsigned short* __restrict__ Xlo) {
  int r = blockIdx.x;
  int row = ids[r];
  int e = threadIdx.x * 4;
  const float4 v = *reinterpret_cast<const float4*>(emb + (size_t)row * EMB + e);
  ushort4 hi, lo;
  hi.x = f2bf(v.x); lo.x = f2bf(v.x - bf2f(hi.x));
  hi.y = f2bf(v.y); lo.y = f2bf(v.y - bf2f(hi.y));
  hi.z = f2bf(v.z); lo.z = f2bf(v.z - bf2f(hi.z));
  hi.w = f2bf(v.w); lo.w = f2bf(v.w - bf2f(hi.w));
  *reinterpret_cast<ushort4*>(Xhi + (size_t)r * EMB + e) = hi;
  *reinterpret_cast<ushort4*>(Xlo + (size_t)r * EMB + e) = lo;
}

// ------------- transpose+split f32 [K][N] -> bf16 hi/lo [N][K] -------------
__global__ void wsplit_kernel(const float* __restrict__ in, unsigned short* __restrict__ hi,
                              unsigned short* __restrict__ lo, int K, int N) {
  __shared__ float t[32][33];
  int n0 = blockIdx.x * 32, k0 = blockIdx.y * 32;
  int tx = threadIdx.x, ty = threadIdx.y;
#pragma unroll
  for (int i = 0; i < 4; ++i)
    t[ty + i * 8][tx] = in[(size_t)(k0 + ty + i * 8) * N + n0 + tx];
  __syncthreads();
#pragma unroll
  for (int i = 0; i < 4; ++i) {
    float v = t[tx][ty + i * 8];
    unsigned short h = f2bf(v);
    hi[(size_t)(n0 + ty + i * 8) * K + k0 + tx] = h;
    lo[(size_t)(n0 + ty + i * 8) * K + k0 + tx] = f2bf(v - bf2f(h));
  }
}

// ------------- transpose f32 [K][N] -> bf16 [N][K] (Wd, r5-validated) -------
__global__ void transpose_kernel(const float* __restrict__ in, unsigned short* __restrict__ out,
                                 int K, int N) {
  __shared__ float t[32][33];
  int n0 = blockIdx.x * 32, k0 = blockIdx.y * 32;
  int tx = threadIdx.x, ty = threadIdx.y;
#pragma unroll
  for (int i = 0; i < 4; ++i)
    t[ty + i * 8][tx] = in[(size_t)(k0 + ty + i * 8) * N + n0 + tx];
  __syncthreads();
#pragma unroll
  for (int i = 0; i < 4; ++i)
    out[(size_t)(n0 + ty + i * 8) * K + k0 + tx] = f2bf(t[tx][ty + i * 8]);
}

// ============ fused 2-layer LSTM: register-resident split-bf16 W, MFMA z-path,
// ring-buffer h exchange + ticket sync (no grid.sync, no L2 invalidation).
// blocks 0..127 layer0, 128..255 layer1. T[0]=L0 ticket, T[32]=L1, T[64]=init.
__global__ __launch_bounds__(512, 2) void lstm_ring(
    const unsigned short* __restrict__ Xhi, const unsigned short* __restrict__ Xlo,
    const unsigned short* __restrict__ W0hi, const unsigned short* __restrict__ W0lo,
    const unsigned short* __restrict__ W1hi, const unsigned short* __restrict__ W1lo,
    const float* __restrict__ b0, const float* __restrict__ b1,
    unsigned short* h1hi, unsigned short* h1lo,   // rings [129][32][1024]
    unsigned short* h2hi, unsigned short* h2lo,   // h2hi ring slot t+1 == H2 row-block t
    unsigned int* T)
{
  __shared__ float zl[8][32][36];            // 36 KB, padded stride vs bank conflicts

  const int tid   = threadIdx.x;
  const int lane  = tid & 63;
  const int w     = tid >> 6;                // wave 0..7, K-range w*256..+256
  const int layer = blockIdx.x >> 7;
  const int wg    = blockIdx.x & 127;
  const int j0    = wg * 8;
  const int lrow  = lane & 15;
  const int klo   = (lane >> 4) * 8;

  const unsigned short* Whi = layer ? W1hi : W0hi;
  const unsigned short* Wlo = layer ? W1lo : W0lo;
  const float*          bias = layer ? b1 : b0;

  // ---- zero ring slot 0 (coherent stores) ----
  {
    unsigned idx = blockIdx.x * 512u + tid;   // [0, 131072)
    if (idx < 65536u) {
      unsigned a = idx >> 14, o = idx & 16383u;
      unsigned int* base = (a == 0) ? (unsigned int*)h1hi
                         : (a == 1) ? (unsigned int*)h1lo
                         : (a == 2) ? (unsigned int*)h2hi
                                    : (unsigned int*)h2lo;
      __hip_atomic_store(base + o, 0u, __ATOMIC_RELAXED, __HIP_MEMORY_SCOPE_AGENT);
    }
  }
  __syncthreads();   // drains the stores (waitcnt before barrier)
  if (tid == 0) __hip_atomic_fetch_add(&T[64], 1u, __ATOMIC_RELEASE, __HIP_MEMORY_SCOPE_AGENT);

  // ---- persistent W fragments (hi+lo, 128 VGPRs) — overlaps others' zeroing ----
  bf16x8 wh[2][8], wl[2][8];
#pragma unroll
  for (int nt = 0; nt < 2; ++nt) {
    int n = nt * 16 + lrow;
    size_t grow = (size_t)((n >> 3) * 1024 + j0 + (n & 7));
    const unsigned short* bh = Whi + grow * 2048 + w * 256 + klo;
    const unsigned short* bl = Wlo + grow * 2048 + w * 256 + klo;
#pragma unroll
    for (int ks = 0; ks < 8; ++ks) {
      wh[nt][ks] = *reinterpret_cast<const bf16x8*>(bh + ks * 32);
      wl[nt][ks] = *reinterpret_cast<const bf16x8*>(bl + ks * 32);
    }
  }

  const int eb = tid >> 3;
  const int ec = tid & 7;
  const float bi  = bias[j0 + ec];
  const float bj  = bias[1024 + j0 + ec];
  const float bff = bias[2048 + j0 + ec];
  const float bo  = bias[3072 + j0 + ec];
  float c = 0.f;

  // wait: all blocks finished slot-0 zeroing
  if (tid == 0) {
    while (__hip_atomic_load(&T[64], __ATOMIC_RELAXED, __HIP_MEMORY_SCOPE_AGENT) < 256u)
      __builtin_amdgcn_s_sleep(1);
  }
  __syncthreads();

  for (int t = 0; t < SEQ; ++t) {
    // ---- ticket wait ----
    if (tid == 0) {
      unsigned tgt0 = layer ? 128u * (t + 1) : 128u * t;
      while (__hip_atomic_load(&T[0], __ATOMIC_RELAXED, __HIP_MEMORY_SCOPE_AGENT) < tgt0)
        __builtin_amdgcn_s_sleep(1);
      if (layer) {
        unsigned tgt1 = 128u * t;
        while (__hip_atomic_load(&T[32], __ATOMIC_RELAXED, __HIP_MEMORY_SCOPE_AGENT) < tgt1)
          __builtin_amdgcn_s_sleep(1);
      }
    }
    __syncthreads();

    // ---- A sources (ring slots are written-once, read-fresh) ----
    const unsigned short *aHi, *aLo;
    if (layer == 0) {
      if (w < 4) { aHi = Xhi + (size_t)t * LSLOT;       aLo = Xlo + (size_t)t * LSLOT; }
      else       { aHi = h1hi + (size_t)t * LSLOT;      aLo = h1lo + (size_t)t * LSLOT; }
    } else {
      if (w < 4) { aHi = h1hi + (size_t)(t + 1) * LSLOT; aLo = h1lo + (size_t)(t + 1) * LSLOT; }
      else       { aHi = h2hi + (size_t)t * LSLOT;      aLo = h2lo + (size_t)t * LSLOT; }
    }
    const int aoff = (w & 3) * 256;
    const unsigned short* aH0 = aHi + (size_t)lrow * 1024 + aoff + klo;
    const unsigned short* aL0 = aLo + (size_t)lrow * 1024 + aoff + klo;
    const unsigned short* aH1 = aH0 + 16 * 1024;
    const unsigned short* aL1 = aL0 + 16 * 1024;

    f32x4 acc[2][2] = {};
#pragma unroll
    for (int ks = 0; ks < 8; ++ks) {
      bf16x8 a0h = *reinterpret_cast<const bf16x8*>(aH0 + ks * 32);
      bf16x8 a0l = *reinterpret_cast<const bf16x8*>(aL0 + ks * 32);
      bf16x8 a1h = *reinterpret_cast<const bf16x8*>(aH1 + ks * 32);
      bf16x8 a1l = *reinterpret_cast<const bf16x8*>(aL1 + ks * 32);
#pragma unroll
      for (int nt = 0; nt < 2; ++nt) {
        acc[0][nt] = __builtin_amdgcn_mfma_f32_16x16x32_bf16(a0h, wh[nt][ks], acc[0][nt], 0, 0, 0);
        acc[0][nt] = __builtin_amdgcn_mfma_f32_16x16x32_bf16(a0l, wh[nt][ks], acc[0][nt], 0, 0, 0);
        acc[0][nt] = __builtin_amdgcn_mfma_f32_16x16x32_bf16(a0h, wl[nt][ks], acc[0][nt], 0, 0, 0);
        acc[1][nt] = __builtin_amdgcn_mfma_f32_16x16x32_bf16(a1h, wh[nt][ks], acc[1][nt], 0, 0, 0);
        acc[1][nt] = __builtin_amdgcn_mfma_f32_16x16x32_bf16(a1l, wh[nt][ks], acc[1][nt], 0, 0, 0);
        acc[1][nt] = __builtin_amdgcn_mfma_f32_16x16x32_bf16(a1h, wl[nt][ks], acc[1][nt], 0, 0, 0);
      }
    }

    // C/D (r5-validated): col = lane&15 (n), row = (lane>>4)*4 + j (batch)
    const int zb = (lane >> 4) * 4;
#pragma unroll
    for (int mt = 0; mt < 2; ++mt)
#pragma unroll
      for (int nt = 0; nt < 2; ++nt)
#pragma unroll
        for (int j = 0; j < 4; ++j)
          zl[w][mt * 16 + zb + j][nt * 16 + lrow] = acc[mt][nt][j];
    __syncthreads();

    if (tid < 256) {
      float iv = bi, jv = bj, fv = bff, ov = bo;
#pragma unroll
      for (int ww = 0; ww < 8; ++ww) {
        iv += zl[ww][eb][ec];
        jv += zl[ww][eb][8 + ec];
        fv += zl[ww][eb][16 + ec];
        ov += zl[ww][eb][24 + ec];
      }
      float si = 1.f / (1.f + expf(-iv));
      float sf = 1.f / (1.f + expf(-(fv + 1.f)));   // FORGET_BIAS = 1.0
      float so = 1.f / (1.f + expf(-ov));
      float tj = tanhf(jv);
      c = c * sf + si * tj;
      float hv = tanhf(c) * so;
      unsigned short hh = f2bf(hv);
      unsigned short hl = f2bf(hv - bf2f(hh));
      // pack (ec, ec+1) into u32, even-ec lanes store coherently into slot t+1
      int hhp = __shfl_xor((int)hh, 1);
      int hlp = __shfl_xor((int)hl, 1);
      if ((ec & 1) == 0) {
        unsigned uhi = (unsigned)hh | ((unsigned)hhp << 16);
        unsigned ulo = (unsigned)hl | ((unsigned)hlp << 16);
        unsigned off = (unsigned)(eb * 1024 + j0 + ec) >> 1;
        unsigned int* dh = (unsigned int*)((layer ? h2hi : h1hi) + (size_t)(t + 1) * LSLOT) + off;
        unsigned int* dl = (unsigned int*)((layer ? h2lo : h1lo) + (size_t)(t + 1) * LSLOT) + off;
        __hip_atomic_store(dh, uhi, __ATOMIC_RELAXED, __HIP_MEMORY_SCOPE_AGENT);
        __hip_atomic_store(dl, ulo, __ATOMIC_RELAXED, __HIP_MEMORY_SCOPE_AGENT);
      }
    }
    __syncthreads();   // drains all threads' coherent stores + zl reads done
    if (tid == 0)
      __hip_atomic_fetch_add(layer ? &T[32] : &T[0], 1u,
                             __ATOMIC_RELEASE, __HIP_MEMORY_SCOPE_AGENT);
  }
}

// ---------------- MFMA dense GEMM (r5-validated): C = A * B^T + bias ----------
__global__ __launch_bounds__(256) void gemm_bt(
    const unsigned short* __restrict__ A, const unsigned short* __restrict__ B,
    const float* __restrict__ bias, float* __restrict__ C, int M, int N, int K)
{
  __shared__ __align__(16) unsigned short As[128 * 32];
  __shared__ __align__(16) unsigned short Bs[128 * 32];
  const int tid = threadIdx.x, lane = tid & 63, w = tid >> 6;

  const int ntiles = gridDim.x;
  int lid = blockIdx.y * ntiles + blockIdx.x;
  int total = ntiles * gridDim.y;
  int cpx = total >> 3;
  int swz = (lid & 7) * cpx + (lid >> 3);
  int bn = swz % ntiles, bm = swz / ntiles;

  const int wm = (w >> 1) * 64, wn = (w & 1) * 64;
  const int lrow = lane & 15, klo = (lane >> 4) * 8;
  const int l4 = lane >> 2, l2 = lane & 3;

  f32x4 acc[4][4] = {};

  for (int kt = 0; kt < K / 32; ++kt) {
    __syncthreads();
#pragma unroll
    for (int ci = 0; ci < 2; ++ci) {
      int row = w * 32 + ci * 16 + l4;
      async16(A + (size_t)(bm * 128 + row) * K + kt * 32 + l2 * 8,
              (char*)As + (w * 2 + ci) * 1024);
      async16(B + (size_t)(bn * 128 + row) * K + kt * 32 + l2 * 8,
              (char*)Bs + (w * 2 + ci) * 1024);
    }
    __syncthreads();
    bf16x8 a[4], bb[4];
#pragma unroll
    for (int i = 0; i < 4; ++i) {
      a[i]  = *reinterpret_cast<const bf16x8*>(As + (wm + i * 16 + lrow) * 32 + klo);
      bb[i] = *reinterpret_cast<const bf16x8*>(Bs + (wn + i * 16 + lrow) * 32 + klo);
    }
#pragma unroll
    for (int i = 0; i < 4; ++i)
#pragma unroll
      for (int j = 0; j < 4; ++j)
        acc[i][j] = __builtin_amdgcn_mfma_f32_16x16x32_bf16(a[i], bb[j], acc[i][j], 0, 0, 0);
  }

#pragma unroll
  for (int j2 = 0; j2 < 4; ++j2) {
    int col = bn * 128 + wn + j2 * 16 + lrow;
    float bv = bias[col];
#pragma unroll
    for (int i = 0; i < 4; ++i) {
      int rbase = bm * 128 + wm + i * 16 + (lane >> 4) * 4;
#pragma unroll
      for (int j = 0; j < 4; ++j)
        C[(size_t)(rbase + j) * N + col] = acc[i][j2][j] + bv;
    }
  }
}

// ================= host =====================================================
extern "C" void kernel_launch(void* const* d_in, const int* in_sizes, int n_in,
                              void* d_out, int out_size, void* d_ws, size_t ws_size,
                              hipStream_t stream) {
  const int*   ids = (const int*)d_in[0];
  const float* emb = (const float*)d_in[1];
  const float* W0  = (const float*)d_in[2];
  const float* b0  = (const float*)d_in[3];
  const float* W1  = (const float*)d_in[4];
  const float* b1  = (const float*)d_in[5];
  const float* Wd  = (const float*)d_in[6];
  const float* bd  = (const float*)d_in[7];
  float* out = (float*)d_out;

  const size_t ringB = (size_t)(SEQ + 1) * LSLOT * 2;   // 8.45 MB per ring

  // d_out scratch (dead until gemm overwrites all of it): X hi/lo + lo-rings
  unsigned short* Xhi   = (unsigned short*)d_out;
  unsigned short* Xlo   = Xhi + (size_t)ROWS * EMB;
  unsigned short* h1lo  = Xlo + (size_t)ROWS * EMB;
  unsigned short* h2lo  = h1lo + (size_t)(SEQ + 1) * LSLOT;

  char* ws = (char*)d_ws;
  size_t off = 0;
  auto alloc = [&](size_t bytes) {
    char* p = ws + off;
    off += (bytes + 255) & ~(size_t)255;
    return p;
  };
  unsigned int*   T    = (unsigned int*)alloc(256);
  unsigned short* h1hi = (unsigned short*)alloc(ringB);
  unsigned short* H2R  = (unsigned short*)alloc(ringB);        // h2-hi ring == H2 output
  size_t regionW = off;
  unsigned short* W0hi = (unsigned short*)alloc((size_t)G4 * 2048 * 2);
  unsigned short* W0lo = (unsigned short*)alloc((size_t)G4 * 2048 * 2);
  unsigned short* W1hi = (unsigned short*)alloc((size_t)G4 * 2048 * 2);
  unsigned short* W1lo = (unsigned short*)alloc((size_t)G4 * 2048 * 2);
  unsigned short* Wdt  = (unsigned short*)(ws + regionW);      // aliases W region post-recurrence
  (void)in_sizes; (void)n_in; (void)out_size; (void)ws_size;   // ws total ~84 MB

  hipMemsetAsync(T, 0, 256, stream);
  embed_split<<<ROWS, 256, 0, stream>>>(ids, emb, Xhi, Xlo);
  wsplit_kernel<<<dim3(G4 / 32, 2048 / 32), dim3(32, 8), 0, stream>>>(W0, W0hi, W0lo, 2048, G4);
  wsplit_kernel<<<dim3(G4 / 32, 2048 / 32), dim3(32, 8), 0, stream>>>(W1, W1hi, W1lo, 2048, G4);

  void* args[] = {(void*)&Xhi, (void*)&Xlo, (void*)&W0hi, (void*)&W0lo,
                  (void*)&W1hi, (void*)&W1lo, (void*)&b0, (void*)&b1,
                  (void*)&h1hi, (void*)&h1lo, (void*)&H2R, (void*)&h2lo, (void*)&T};
  hipError_t rc = hipLaunchCooperativeKernel((void*)lstm_ring, dim3(256), dim3(512),
                                             args, 0, stream);
  if (rc != hipSuccess) {
    // ticket sync needs co-residency only; 1 block/CU x 256 CUs => normal launch safe
    lstm_ring<<<256, 512, 0, stream>>>(Xhi, Xlo, W0hi, W0lo, W1hi, W1lo, b0, b1,
                                       h1hi, h1lo, H2R, h2lo, T);
  }

  transpose_kernel<<<dim3(VOCAB / 32, HID / 32), dim3(32, 8), 0, stream>>>(Wd, Wdt, HID, VOCAB);
  gemm_bt<<<dim3(VOCAB / 128, ROWS / 128), 256, 0, stream>>>(H2R + LSLOT, Wdt, bd, out,
                                                             ROWS, VOCAB, HID);
}